// Round 12
// baseline (668.188 us; speedup 1.0000x reference)
//
#include <hip/hip_runtime.h>
#include <hip/hip_bf16.h>
#include <hip/hip_fp8.h>

#define PI_F 3.14159265358979323846f
#define NBLK 256     // blocks for count/scatter passes
#define BSH 8        // coarse bucket = 256 dst nodes
#define BSZ 256      // nodes per bucket
#define SCAP 10240   // LDS edge staging capacity (mean 8192, +22 sigma)

static inline size_t align256(size_t x) { return (x + 255) & ~size_t(255); }

typedef float v2f __attribute__((ext_vector_type(2)));

// ---------------- atomic-free bucketed CSR build ----------------

__global__ void count_kernel(const int* __restrict__ dst, int* __restrict__ C,
                             int E, int CHUNK, int NB2) {
    extern __shared__ int hist[];   // NB2 ints
    for (int i = threadIdx.x; i < NB2; i += 256) hist[i] = 0;
    __syncthreads();
    int s0 = blockIdx.x * CHUNK, s1 = min(s0 + CHUNK, E);
    for (int e = s0 + threadIdx.x; e < s1; e += 256)
        atomicAdd(&hist[dst[e] >> BSH], 1);
    __syncthreads();
    for (int i = threadIdx.x; i < NB2; i += 256)
        C[(size_t)blockIdx.x * NB2 + i] = hist[i];
}

__global__ void scan_blocks_kernel(int* __restrict__ C, int* __restrict__ colsum, int NB2) {
    __shared__ int s[256];
    int k = blockIdx.x;
    int b = threadIdx.x;
    int v = C[(size_t)b * NB2 + k];
    s[b] = v;
    __syncthreads();
    for (int off = 1; off < 256; off <<= 1) {
        int w = (b >= off) ? s[b - off] : 0;
        __syncthreads();
        s[b] += w;
        __syncthreads();
    }
    C[(size_t)b * NB2 + k] = s[b] - v;   // exclusive
    if (b == 255) colsum[k] = s[255];
}

__global__ void scan_totals_kernel(const int* __restrict__ colsum, int* __restrict__ bbase,
                                   int NB2, int E) {
    __shared__ int s[256];
    __shared__ int running;
    if (threadIdx.x == 0) running = 0;
    __syncthreads();
    for (int base = 0; base < NB2; base += 256) {
        int i = base + threadIdx.x;
        int v = (i < NB2) ? colsum[i] : 0;
        s[threadIdx.x] = v;
        __syncthreads();
        for (int off = 1; off < 256; off <<= 1) {
            int w = (threadIdx.x >= (unsigned)off) ? s[threadIdx.x - off] : 0;
            __syncthreads();
            s[threadIdx.x] += w;
            __syncthreads();
        }
        if (i < NB2) bbase[i] = running + s[threadIdx.x] - v;
        __syncthreads();
        if (threadIdx.x == 255) running += s[255];
        __syncthreads();
    }
    if (threadIdx.x == 0) bbase[NB2] = E;
}

__global__ void scatter_kernel(const int* __restrict__ src, const int* __restrict__ dst,
                               const int* __restrict__ C, const int* __restrict__ bbase,
                               unsigned* __restrict__ bkt_data, int E, int CHUNK, int NB2) {
    extern __shared__ int ofs[];   // NB2 ints
    for (int i = threadIdx.x; i < NB2; i += 256)
        ofs[i] = bbase[i] + C[(size_t)blockIdx.x * NB2 + i];
    __syncthreads();
    int s0 = blockIdx.x * CHUNK, s1 = min(s0 + CHUNK, E);
    for (int e = s0 + threadIdx.x; e < s1; e += 256) {
        int d = dst[e];
        int p = atomicAdd(&ofs[d >> BSH], 1);   // LDS atomic only
        bkt_data[p] = ((unsigned)(d & (BSZ - 1)) << 17) | (unsigned)src[e];
    }
}

__global__ void csr_build_kernel(const unsigned* __restrict__ bkt_data, const int* __restrict__ bbase,
                                 const float* __restrict__ x,
                                 unsigned* __restrict__ csr, int* __restrict__ e_start,
                                 float* __restrict__ dinv, float* __restrict__ xd,
                                 int N, int NB2) {
    __shared__ unsigned sdata[SCAP];
    __shared__ int hist[256];
    __shared__ int scn[256];
    __shared__ int bump[256];
    int b = blockIdx.x;
    int g0 = bbase[b], g1 = bbase[b + 1];
    int cnt = g1 - g0;
    bool fits = (cnt <= SCAP);
    hist[threadIdx.x] = 0;
    __syncthreads();
    for (int i = threadIdx.x; i < cnt; i += 256) {
        unsigned pk = bkt_data[g0 + i];
        if (fits) sdata[i] = pk;
        atomicAdd(&hist[pk >> 17], 1);
    }
    __syncthreads();
    int orig = hist[threadIdx.x];
    scn[threadIdx.x] = orig;
    __syncthreads();
    for (int off = 1; off < 256; off <<= 1) {
        int w = (threadIdx.x >= (unsigned)off) ? scn[threadIdx.x - off] : 0;
        __syncthreads();
        scn[threadIdx.x] += w;
        __syncthreads();
    }
    int excl = scn[threadIdx.x] - orig;
    bump[threadIdx.x] = g0 + excl;
    int node = b * BSZ + threadIdx.x;
    if (node < N) {
        float dv = rsqrtf((float)(orig + 1));
        dinv[node] = dv;
        xd[node] = x[node] * dv;
        e_start[node] = g0 + excl;
    }
    if (b == NB2 - 1 && threadIdx.x == 0) e_start[N] = g1;
    __syncthreads();
    for (int i = threadIdx.x; i < cnt; i += 256) {
        unsigned pk = fits ? sdata[i] : bkt_data[g0 + i];
        int p = atomicAdd(&bump[pk >> 17], 1);
        csr[p] = pk & 0x1FFFFu;
    }
}

// ---------------- GCN layers ----------------
// u rows: per-row-scaled fp8 e4m3 (OCP): u8[node][32] + uscale[node] f32.

// Layer 1 (rank-1): sum_src u1[src][f] = (sum xd[src])*W1[f]; scalar xd gather.
__global__ void agg1_kernel(const float* __restrict__ xd, const int* __restrict__ e_start,
                            const unsigned* __restrict__ csr, const float* __restrict__ dinv,
                            const float* __restrict__ W1, const float* __restrict__ b1,
                            const float* __restrict__ W2,
                            unsigned char* __restrict__ u8out, float* __restrict__ uscale, int n) {
    __shared__ float sW2[1024];
    __shared__ float sW1[32], sb1[32];
    for (int i = threadIdx.x; i < 1024; i += 256) sW2[i] = W2[i];
    if (threadIdx.x < 32) { sW1[threadIdx.x] = W1[threadIdx.x]; sb1[threadIdx.x] = b1[threadIdx.x]; }
    __syncthreads();
    int t = blockIdx.x * 256 + threadIdx.x;
    int d = t >> 6;
    int lane = threadIdx.x & 63;
    if (d >= n) return;
    int e0 = e_start[d];
    int cnt = e_start[d + 1] - e0;
    float s = 0.f;
    for (int j = lane; j < cnt; j += 64) s += xd[csr[e0 + j]];
#pragma unroll
    for (int m = 1; m < 64; m <<= 1) s += __shfl_xor(s, m, 64);
    float dv = dinv[d];
    float tt = dv * (s + xd[d]);
    int f = lane & 31, half = lane >> 5;
    float h1 = fmaxf(tt * sW1[f] + sb1[f], 0.f);   // replicated in both halves
    float p = 0.f;
    int k0 = half << 4;
#pragma unroll
    for (int k = 0; k < 16; k++) p += __shfl(h1, k0 + k, 64) * sW2[(k0 + k) * 32 + f];
    p += __shfl_xor(p, 32, 64);
    float outv = dv * p;
    float am = fabsf(outv);
#pragma unroll
    for (int m = 1; m < 32; m <<= 1) am = fmaxf(am, __shfl_xor(am, m, 64));
    float rm = fmaxf(am, 1e-20f);
    float sc = 128.f / rm;
    if (half == 0) {
        __hip_fp8_e4m3 qv(outv * sc);
        u8out[(size_t)d * 32 + f] = (unsigned char)qv.__x;
        if (f == 0) uscale[d] = rm * (1.f / 128.f);
    }
}

// Two nodes per wave; il=lane&31, slot=il>>3.. no: slot=il>>3? (kept: slot=il>>3 is 4 slots)
// slot = il>>3 (4 edge slots), q = il&7 (8 feature quads).
// Gather loop: up to 64 edges preloaded (2x csr + 2x uscale up-front); inner
// rounds are mask-free (dead lanes have rs=0) and #pragma unroll 4 for MLP.
#define AGG_GATHER_BODY(SVREG, RSREG, IOFF)                                          \
    {                                                                                \
        int s = __shfl(SVREG, hb | ((IOFF) & 31), 64);                               \
        float rs = __shfl(RSREG, hb | ((IOFF) & 31), 64);                            \
        unsigned w = *(const unsigned*)(u8 + ((size_t)s << 5) + (q << 2));           \
        v2f lo = __builtin_amdgcn_cvt_pk_f32_fp8(w, false);                          \
        v2f hi = __builtin_amdgcn_cvt_pk_f32_fp8(w, true);                           \
        a0 += rs * lo.x; a1 += rs * lo.y; a2 += rs * hi.x; a3 += rs * hi.y;          \
    }

// agg2: out = fp8rows(dinv*(relu(agg)@W))
__global__ void agg2_kernel(const unsigned char* __restrict__ u8, const float* __restrict__ uscale,
                            const int* __restrict__ e_start, const unsigned* __restrict__ csr,
                            const float* __restrict__ dinv, const float* __restrict__ bias,
                            const float* __restrict__ W,
                            unsigned char* __restrict__ o8, float* __restrict__ oscale, int n) {
    int t = blockIdx.x * 256 + threadIdx.x;
    int d = t >> 5;                      // one node per 32-lane half
    int lane = threadIdx.x & 63;
    int il = lane & 31;
    int hb = lane & 32;
    int slot = il >> 3, q = il & 7;
    float4 Wr[8];
#pragma unroll
    for (int j = 0; j < 8; j++) Wr[j] = *(const float4*)(W + (slot * 8 + j) * 32 + q * 4);
    float4 bq = *(const float4*)(bias + q * 4);
    bool act = (d < n);
    int e0 = 0, cnt = 0;
    float dv = 0.f;
    if (act) { e0 = e_start[d]; cnt = e_start[d + 1] - e0; dv = dinv[d]; }
    float a0 = 0.f, a1 = 0.f, a2 = 0.f, a3 = 0.f;
    for (int c = 0; c < cnt; c += 64) {
        int rem = cnt - c; if (rem > 64) rem = 64;
        int sv0 = 0, sv1 = 0; float rs0 = 0.f, rs1 = 0.f;
        if (il < rem)      { sv0 = (int)csr[e0 + c + il];      rs0 = uscale[sv0]; }
        if (il + 32 < rem) { sv1 = (int)csr[e0 + c + 32 + il]; rs1 = uscale[sv1]; }
        int R = (rem + 7) >> 3;          // rounds over first chunk: i = slot + 8r? no: stride 8 slots? slot stride is 8 (4 slots x step)...
        // 4 slots, stride 4: rounds over chunk0
        int R0 = rem > 32 ? 8 : ((rem + 3) >> 2);
#pragma unroll 4
        for (int r = 0; r < R0; r++) AGG_GATHER_BODY(sv0, rs0, slot + (r << 2))
        if (rem > 32) {
            int R1 = ((rem - 32) + 3) >> 2;
#pragma unroll 4
            for (int r = 0; r < R1; r++) AGG_GATHER_BODY(sv1, rs1, slot + (r << 2))
        }
        (void)R;
    }
#pragma unroll
    for (int m = 8; m < 32; m <<= 1) {   // reduce over 4 slots (within half)
        a0 += __shfl_xor(a0, m, 64); a1 += __shfl_xor(a1, m, 64);
        a2 += __shfl_xor(a2, m, 64); a3 += __shfl_xor(a3, m, 64);
    }
    if (act) {   // self row
        float rs = uscale[d];
        unsigned w = *(const unsigned*)(u8 + ((size_t)d << 5) + (q << 2));
        v2f lo = __builtin_amdgcn_cvt_pk_f32_fp8(w, false);
        v2f hi = __builtin_amdgcn_cvt_pk_f32_fp8(w, true);
        a0 += rs * lo.x; a1 += rs * lo.y; a2 += rs * hi.x; a3 += rs * hi.y;
    }
    float v0 = fmaxf(dv * a0 + bq.x, 0.f);
    float v1 = fmaxf(dv * a1 + bq.y, 0.f);
    float v2 = fmaxf(dv * a2 + bq.z, 0.f);
    float v3 = fmaxf(dv * a3 + bq.w, 0.f);
    float p0 = 0.f, p1 = 0.f, p2 = 0.f, p3 = 0.f;
#pragma unroll
    for (int j = 0; j < 8; j++) {
        int srcl = hb | (slot << 1) | (j >> 2);
        float vk;
        switch (j & 3) {
            case 0: vk = __shfl(v0, srcl, 64); break;
            case 1: vk = __shfl(v1, srcl, 64); break;
            case 2: vk = __shfl(v2, srcl, 64); break;
            default: vk = __shfl(v3, srcl, 64); break;
        }
        p0 += vk * Wr[j].x; p1 += vk * Wr[j].y; p2 += vk * Wr[j].z; p3 += vk * Wr[j].w;
    }
#pragma unroll
    for (int m = 8; m < 32; m <<= 1) {
        p0 += __shfl_xor(p0, m, 64); p1 += __shfl_xor(p1, m, 64);
        p2 += __shfl_xor(p2, m, 64); p3 += __shfl_xor(p3, m, 64);
    }
    float o0 = dv * p0, o1 = dv * p1, o2 = dv * p2, o3 = dv * p3;
    float am = fmaxf(fmaxf(fabsf(o0), fabsf(o1)), fmaxf(fabsf(o2), fabsf(o3)));
#pragma unroll
    for (int m = 1; m < 32; m <<= 1) am = fmaxf(am, __shfl_xor(am, m, 64));
    float rm = fmaxf(am, 1e-20f);
    float sc = 128.f / rm;
    int u = 0;
    u = __builtin_amdgcn_cvt_pk_fp8_f32(o0 * sc, o1 * sc, u, false);
    u = __builtin_amdgcn_cvt_pk_fp8_f32(o2 * sc, o3 * sc, u, true);
    if (act && slot == 0) {
        *(unsigned*)(o8 + ((size_t)d << 5) + (q << 2)) = (unsigned)u;
        if (q == 0) oscale[d] = rm * (1.f / 128.f);
    }
}

// agg3: h = relu(agg) (fp32) + fused theta head; two nodes per wave.
__global__ void agg3_kernel(const unsigned char* __restrict__ u8, const float* __restrict__ uscale,
                            const int* __restrict__ e_start, const unsigned* __restrict__ csr,
                            const float* __restrict__ dinv, const float* __restrict__ bias,
                            const float* __restrict__ Wt1, const float* __restrict__ bt1,
                            const float* __restrict__ Wt2, const float* __restrict__ bt2,
                            float* __restrict__ hout, float* __restrict__ theta, int n) {
    int t = blockIdx.x * 256 + threadIdx.x;
    int d = t >> 5;
    int lane = threadIdx.x & 63;
    int il = lane & 31;
    int hb = lane & 32;
    int slot = il >> 3, q = il & 7;
    float4 Wr[8];
#pragma unroll
    for (int j = 0; j < 8; j++) Wr[j] = *(const float4*)(Wt1 + (slot * 8 + j) * 32 + q * 4);
    float4 bq = *(const float4*)(bias + q * 4);
    float4 bt = *(const float4*)(bt1 + q * 4);
    float4 w2 = *(const float4*)(Wt2 + q * 4);
    float bt2v = bt2[0];
    bool act = (d < n);
    int e0 = 0, cnt = 0;
    float dv = 0.f;
    if (act) { e0 = e_start[d]; cnt = e_start[d + 1] - e0; dv = dinv[d]; }
    float a0 = 0.f, a1 = 0.f, a2 = 0.f, a3 = 0.f;
    for (int c = 0; c < cnt; c += 64) {
        int rem = cnt - c; if (rem > 64) rem = 64;
        int sv0 = 0, sv1 = 0; float rs0 = 0.f, rs1 = 0.f;
        if (il < rem)      { sv0 = (int)csr[e0 + c + il];      rs0 = uscale[sv0]; }
        if (il + 32 < rem) { sv1 = (int)csr[e0 + c + 32 + il]; rs1 = uscale[sv1]; }
        int R0 = rem > 32 ? 8 : ((rem + 3) >> 2);
#pragma unroll 4
        for (int r = 0; r < R0; r++) AGG_GATHER_BODY(sv0, rs0, slot + (r << 2))
        if (rem > 32) {
            int R1 = ((rem - 32) + 3) >> 2;
#pragma unroll 4
            for (int r = 0; r < R1; r++) AGG_GATHER_BODY(sv1, rs1, slot + (r << 2))
        }
    }
#pragma unroll
    for (int m = 8; m < 32; m <<= 1) {
        a0 += __shfl_xor(a0, m, 64); a1 += __shfl_xor(a1, m, 64);
        a2 += __shfl_xor(a2, m, 64); a3 += __shfl_xor(a3, m, 64);
    }
    if (act) {
        float rs = uscale[d];
        unsigned w = *(const unsigned*)(u8 + ((size_t)d << 5) + (q << 2));
        v2f lo = __builtin_amdgcn_cvt_pk_f32_fp8(w, false);
        v2f hi = __builtin_amdgcn_cvt_pk_f32_fp8(w, true);
        a0 += rs * lo.x; a1 += rs * lo.y; a2 += rs * hi.x; a3 += rs * hi.y;
    }
    float v0 = fmaxf(dv * a0 + bq.x, 0.f);
    float v1 = fmaxf(dv * a1 + bq.y, 0.f);
    float v2 = fmaxf(dv * a2 + bq.z, 0.f);
    float v3 = fmaxf(dv * a3 + bq.w, 0.f);
    if (act && slot == 0) *(float4*)(hout + ((size_t)d << 5) + (q << 2)) = make_float4(v0, v1, v2, v3);
    float p0 = 0.f, p1 = 0.f, p2 = 0.f, p3 = 0.f;
#pragma unroll
    for (int j = 0; j < 8; j++) {
        int srcl = hb | (slot << 1) | (j >> 2);
        float vk;
        switch (j & 3) {
            case 0: vk = __shfl(v0, srcl, 64); break;
            case 1: vk = __shfl(v1, srcl, 64); break;
            case 2: vk = __shfl(v2, srcl, 64); break;
            default: vk = __shfl(v3, srcl, 64); break;
        }
        p0 += vk * Wr[j].x; p1 += vk * Wr[j].y; p2 += vk * Wr[j].z; p3 += vk * Wr[j].w;
    }
#pragma unroll
    for (int m = 8; m < 32; m <<= 1) {
        p0 += __shfl_xor(p0, m, 64); p1 += __shfl_xor(p1, m, 64);
        p2 += __shfl_xor(p2, m, 64); p3 += __shfl_xor(p3, m, 64);
    }
    float tl = fmaxf(p0 + bt.x, 0.f) * w2.x + fmaxf(p1 + bt.y, 0.f) * w2.y
             + fmaxf(p2 + bt.z, 0.f) * w2.z + fmaxf(p3 + bt.w, 0.f) * w2.w;
#pragma unroll
    for (int m = 1; m < 8; m <<= 1) tl += __shfl_xor(tl, m, 64);
    if (act && il == 0) theta[d] = PI_F / (1.f + __expf(-(tl + bt2v)));
}

// ---------------- heads ----------------

__global__ void pool_kernel(const float* __restrict__ h, const int* __restrict__ batch,
                            float* __restrict__ gsum, float* __restrict__ gcnt, int n) {
    int f = threadIdx.x & 31;
    int sub = threadIdx.x >> 5;
    int start = blockIdx.x * 1024 + sub * 128;
    int end = min(start + 128, n);
    if (start >= end) return;
    int curg = batch[start];
    float acc = 0.f;
    int cnt = 0;
    for (int i = start; i < end; i++) {
        int g = batch[i];
        if (g != curg) {
            atomicAdd(&gsum[curg * 32 + f], acc);
            if (f == 0) atomicAdd(&gcnt[curg], (float)cnt);
            acc = 0.f; cnt = 0; curg = g;
        }
        acc += h[i * 32 + f];
        cnt++;
    }
    atomicAdd(&gsum[curg * 32 + f], acc);
    if (f == 0) atomicAdd(&gcnt[curg], (float)cnt);
}

__global__ void bg_kernel(const float* __restrict__ gsum, const float* __restrict__ gcnt,
                          const float* __restrict__ Wg1, const float* __restrict__ bg1,
                          const float* __restrict__ Wg2, const float* __restrict__ bg2,
                          float* __restrict__ out, int G) {
    __shared__ float sW[1024];
    for (int i = threadIdx.x; i < 1024; i += 256) sW[i] = Wg1[i];
    __syncthreads();
    int t = blockIdx.x * 256 + threadIdx.x;
    int g = t >> 5;
    int lane = threadIdx.x & 63;
    int f = lane & 31, base = lane & 32;
    if (g >= G) return;
    float cnt = fmaxf(gcnt[g], 1.f);
    float hv = gsum[g * 32 + f] / cnt;
    float a = bg1[f];
#pragma unroll
    for (int k = 0; k < 32; k++) a += __shfl(hv, base | k, 64) * sW[k * 32 + f];
    a = fmaxf(a, 0.f);
    float p0 = a * Wg2[f * 2 + 0];
    float p1 = a * Wg2[f * 2 + 1];
    for (int m = 1; m < 32; m <<= 1) {
        p0 += __shfl_xor(p0, m, 64);
        p1 += __shfl_xor(p1, m, 64);
    }
    if (f == 0) {
        out[g * 2 + 0] = 2.f * PI_F / (1.f + __expf(-(p0 + bg2[0])));
        out[g * 2 + 1] = 2.f * PI_F / (1.f + __expf(-(p1 + bg2[1])));
    }
}

// ---------------- launch ----------------

extern "C" void kernel_launch(void* const* d_in, const int* in_sizes, int n_in,
                              void* d_out, int out_size, void* d_ws, size_t ws_size,
                              hipStream_t stream) {
    const float* x   = (const float*)d_in[0];
    const int*   ei  = (const int*)d_in[1];
    const int* batch = (const int*)d_in[2];
    const float* W1  = (const float*)d_in[3];
    const float* b1  = (const float*)d_in[4];
    const float* W2  = (const float*)d_in[5];
    const float* b2  = (const float*)d_in[6];
    const float* W3  = (const float*)d_in[7];
    const float* b3  = (const float*)d_in[8];
    const float* Wt1 = (const float*)d_in[9];
    const float* bt1 = (const float*)d_in[10];
    const float* Wt2 = (const float*)d_in[11];
    const float* bt2 = (const float*)d_in[12];
    const float* Wg1 = (const float*)d_in[13];
    const float* bg1 = (const float*)d_in[14];
    const float* Wg2 = (const float*)d_in[15];
    const float* bg2 = (const float*)d_in[16];

    const int N = in_sizes[0];
    const int E = in_sizes[1] / 2;
    const int G = 128;
    const int* src = ei;
    const int* dst = ei + E;
    float* theta_out = (float*)d_out;
    float* bg_out = (float*)d_out + N;

    const int NB2 = (N + BSZ - 1) >> BSH;
    const int CHUNK = (E + NBLK - 1) / NBLK;

    char* w = (char*)d_ws;
    auto alloc = [&](size_t bytes) -> char* { char* p = w; w += align256(bytes); return p; };
    int*      C        = (int*)alloc((size_t)NBLK * NB2 * 4);
    int*      colsum   = (int*)alloc((size_t)NB2 * 4);
    int*      bbase    = (int*)alloc((size_t)(NB2 + 1) * 4);
    unsigned* bkt_data = (unsigned*)alloc((size_t)E * 4);
    unsigned* csr      = (unsigned*)alloc((size_t)E * 4);
    int*      e_start  = (int*)alloc((size_t)(N + 1) * 4);
    float*    dinv     = (float*)alloc((size_t)N * 4);
    float*    xd       = (float*)alloc((size_t)N * 4);
    unsigned char* u2  = (unsigned char*)alloc((size_t)N * 32);
    float*    us2      = (float*)alloc((size_t)N * 4);
    unsigned char* u3  = (unsigned char*)alloc((size_t)N * 32);
    float*    us3      = (float*)alloc((size_t)N * 4);
    float*    hbuf     = (float*)alloc((size_t)N * 32 * 4);
    float*    gsum     = (float*)alloc((size_t)G * 32 * 4);
    float*    gcnt     = (float*)alloc((size_t)G * 4);

    hipMemsetAsync(gsum, 0, (size_t)G * 32 * 4, stream);
    hipMemsetAsync(gcnt, 0, (size_t)G * 4, stream);

    size_t ldsB = (size_t)NB2 * 4;
    count_kernel<<<NBLK, 256, ldsB, stream>>>(dst, C, E, CHUNK, NB2);
    scan_blocks_kernel<<<NB2, 256, 0, stream>>>(C, colsum, NB2);
    scan_totals_kernel<<<1, 256, 0, stream>>>(colsum, bbase, NB2, E);
    scatter_kernel<<<NBLK, 256, ldsB, stream>>>(src, dst, C, bbase, bkt_data, E, CHUNK, NB2);
    csr_build_kernel<<<NB2, 256, 0, stream>>>(bkt_data, bbase, x, csr, e_start, dinv, xd, N, NB2);

    unsigned gridNW = (unsigned)(((size_t)N * 64 + 255) / 256);  // one wave per node (agg1)
    unsigned gridNH = (unsigned)(((size_t)N * 32 + 255) / 256);  // two nodes per wave (agg2/3)

    // layer 1 (rank-1 collapse) -> fused W2 -> u2 (fp8+scale)
    agg1_kernel<<<gridNW, 256, 0, stream>>>(xd, e_start, csr, dinv, W1, b1, W2, u2, us2, N);
    // layer 2 -> fused W3 -> u3 (fp8+scale)
    agg2_kernel<<<gridNH, 256, 0, stream>>>(u2, us2, e_start, csr, dinv, b2, W3, u3, us3, N);
    // layer 3 -> h (fp32) + fused theta head
    agg3_kernel<<<gridNH, 256, 0, stream>>>(u3, us3, e_start, csr, dinv, b3,
                                            Wt1, bt1, Wt2, bt2, hbuf, theta_out, N);

    // pooled head
    pool_kernel<<<(N + 1023) / 1024, 256, 0, stream>>>(hbuf, batch, gsum, gcnt, N);
    bg_kernel<<<(G * 32 + 255) / 256, 256, 0, stream>>>(gsum, gcnt, Wg1, bg1, Wg2, bg2, bg_out, G);
}

// Round 13
// 390.820 us; speedup vs baseline: 1.7097x; 1.7097x over previous
//
#include <hip/hip_runtime.h>
#include <hip/hip_bf16.h>
#include <hip/hip_fp8.h>

#define PI_F 3.14159265358979323846f
#define NBLK 256     // blocks for count/scatter passes
#define BSH 8        // coarse bucket = 256 dst nodes
#define BSZ 256      // nodes per bucket
#define SCAP 10240   // LDS edge staging capacity (mean 8192, +22 sigma)

static inline size_t align256(size_t x) { return (x + 255) & ~size_t(255); }

typedef float v2f __attribute__((ext_vector_type(2)));

// ---------------- atomic-free bucketed CSR build ----------------

__global__ void count_kernel(const int* __restrict__ dst, int* __restrict__ C,
                             int E, int CHUNK, int NB2) {
    extern __shared__ int hist[];   // NB2 ints
    for (int i = threadIdx.x; i < NB2; i += 256) hist[i] = 0;
    __syncthreads();
    int s0 = blockIdx.x * CHUNK, s1 = min(s0 + CHUNK, E);
    for (int e = s0 + threadIdx.x; e < s1; e += 256)
        atomicAdd(&hist[dst[e] >> BSH], 1);
    __syncthreads();
    for (int i = threadIdx.x; i < NB2; i += 256)
        C[(size_t)blockIdx.x * NB2 + i] = hist[i];
}

__global__ void scan_blocks_kernel(int* __restrict__ C, int* __restrict__ colsum, int NB2) {
    __shared__ int s[256];
    int k = blockIdx.x;
    int b = threadIdx.x;
    int v = C[(size_t)b * NB2 + k];
    s[b] = v;
    __syncthreads();
    for (int off = 1; off < 256; off <<= 1) {
        int w = (b >= off) ? s[b - off] : 0;
        __syncthreads();
        s[b] += w;
        __syncthreads();
    }
    C[(size_t)b * NB2 + k] = s[b] - v;   // exclusive
    if (b == 255) colsum[k] = s[255];
}

__global__ void scan_totals_kernel(const int* __restrict__ colsum, int* __restrict__ bbase,
                                   int NB2, int E) {
    __shared__ int s[256];
    __shared__ int running;
    if (threadIdx.x == 0) running = 0;
    __syncthreads();
    for (int base = 0; base < NB2; base += 256) {
        int i = base + threadIdx.x;
        int v = (i < NB2) ? colsum[i] : 0;
        s[threadIdx.x] = v;
        __syncthreads();
        for (int off = 1; off < 256; off <<= 1) {
            int w = (threadIdx.x >= (unsigned)off) ? s[threadIdx.x - off] : 0;
            __syncthreads();
            s[threadIdx.x] += w;
            __syncthreads();
        }
        if (i < NB2) bbase[i] = running + s[threadIdx.x] - v;
        __syncthreads();
        if (threadIdx.x == 255) running += s[255];
        __syncthreads();
    }
    if (threadIdx.x == 0) bbase[NB2] = E;
}

__global__ void scatter_kernel(const int* __restrict__ src, const int* __restrict__ dst,
                               const int* __restrict__ C, const int* __restrict__ bbase,
                               unsigned* __restrict__ bkt_data, int E, int CHUNK, int NB2) {
    extern __shared__ int ofs[];   // NB2 ints
    for (int i = threadIdx.x; i < NB2; i += 256)
        ofs[i] = bbase[i] + C[(size_t)blockIdx.x * NB2 + i];
    __syncthreads();
    int s0 = blockIdx.x * CHUNK, s1 = min(s0 + CHUNK, E);
    for (int e = s0 + threadIdx.x; e < s1; e += 256) {
        int d = dst[e];
        int p = atomicAdd(&ofs[d >> BSH], 1);   // LDS atomic only
        bkt_data[p] = ((unsigned)(d & (BSZ - 1)) << 17) | (unsigned)src[e];
    }
}

__global__ void csr_build_kernel(const unsigned* __restrict__ bkt_data, const int* __restrict__ bbase,
                                 const float* __restrict__ x,
                                 unsigned* __restrict__ csr, int* __restrict__ e_start,
                                 float* __restrict__ dinv, float* __restrict__ xd,
                                 int N, int NB2) {
    __shared__ unsigned sdata[SCAP];
    __shared__ int hist[256];
    __shared__ int scn[256];
    __shared__ int bump[256];
    int b = blockIdx.x;
    int g0 = bbase[b], g1 = bbase[b + 1];
    int cnt = g1 - g0;
    bool fits = (cnt <= SCAP);
    hist[threadIdx.x] = 0;
    __syncthreads();
    for (int i = threadIdx.x; i < cnt; i += 256) {
        unsigned pk = bkt_data[g0 + i];
        if (fits) sdata[i] = pk;
        atomicAdd(&hist[pk >> 17], 1);
    }
    __syncthreads();
    int orig = hist[threadIdx.x];
    scn[threadIdx.x] = orig;
    __syncthreads();
    for (int off = 1; off < 256; off <<= 1) {
        int w = (threadIdx.x >= (unsigned)off) ? scn[threadIdx.x - off] : 0;
        __syncthreads();
        scn[threadIdx.x] += w;
        __syncthreads();
    }
    int excl = scn[threadIdx.x] - orig;
    bump[threadIdx.x] = g0 + excl;
    int node = b * BSZ + threadIdx.x;
    if (node < N) {
        float dv = rsqrtf((float)(orig + 1));
        dinv[node] = dv;
        xd[node] = x[node] * dv;
        e_start[node] = g0 + excl;
    }
    if (b == NB2 - 1 && threadIdx.x == 0) e_start[N] = g1;
    __syncthreads();
    for (int i = threadIdx.x; i < cnt; i += 256) {
        unsigned pk = fits ? sdata[i] : bkt_data[g0 + i];
        int p = atomicAdd(&bump[pk >> 17], 1);
        csr[p] = pk & 0x1FFFFu;
    }
}

// ---------------- GCN layers ----------------
// u rows: per-row-scaled fp8 e4m3 (OCP): u8[node][32] + uscale[node] f32.

// Layer 1 (rank-1): sum_src u1[src][f] = (sum xd[src])*W1[f]; scalar xd gather.
__global__ void agg1_kernel(const float* __restrict__ xd, const int* __restrict__ e_start,
                            const unsigned* __restrict__ csr, const float* __restrict__ dinv,
                            const float* __restrict__ W1, const float* __restrict__ b1,
                            const float* __restrict__ W2,
                            unsigned char* __restrict__ u8out, float* __restrict__ uscale, int n) {
    __shared__ float sW2[1024];
    __shared__ float sW1[32], sb1[32];
    for (int i = threadIdx.x; i < 1024; i += 256) sW2[i] = W2[i];
    if (threadIdx.x < 32) { sW1[threadIdx.x] = W1[threadIdx.x]; sb1[threadIdx.x] = b1[threadIdx.x]; }
    __syncthreads();
    int t = blockIdx.x * 256 + threadIdx.x;
    int d = t >> 6;
    int lane = threadIdx.x & 63;
    if (d >= n) return;
    int e0 = e_start[d];
    int cnt = e_start[d + 1] - e0;
    float s = 0.f;
    for (int j = lane; j < cnt; j += 64) s += xd[csr[e0 + j]];
#pragma unroll
    for (int m = 1; m < 64; m <<= 1) s += __shfl_xor(s, m, 64);
    float dv = dinv[d];
    float tt = dv * (s + xd[d]);
    int f = lane & 31, half = lane >> 5;
    float h1 = fmaxf(tt * sW1[f] + sb1[f], 0.f);   // replicated in both halves
    float p = 0.f;
    int k0 = half << 4;
#pragma unroll
    for (int k = 0; k < 16; k++) p += __shfl(h1, k0 + k, 64) * sW2[(k0 + k) * 32 + f];
    p += __shfl_xor(p, 32, 64);
    float outv = dv * p;
    float am = fabsf(outv);
#pragma unroll
    for (int m = 1; m < 32; m <<= 1) am = fmaxf(am, __shfl_xor(am, m, 64));
    float rm = fmaxf(am, 1e-20f);
    float sc = 128.f / rm;
    if (half == 0) {
        __hip_fp8_e4m3 qv(outv * sc);
        u8out[(size_t)d * 32 + f] = (unsigned char)qv.__x;
        if (f == 0) uscale[d] = rm * (1.f / 128.f);
    }
}

// Two nodes per wave: each 32-lane half handles one dst node.
// il = lane&31; slot = il>>3 (4 edge slots), q = il&7 (8 feature quads).
// W tile in registers: lane holds W[slot*8+j][q*4..+3], j=0..7.
// agg2: out = fp8rows(dinv*(relu(agg)@W))
__global__ void agg2_kernel(const unsigned char* __restrict__ u8, const float* __restrict__ uscale,
                            const int* __restrict__ e_start, const unsigned* __restrict__ csr,
                            const float* __restrict__ dinv, const float* __restrict__ bias,
                            const float* __restrict__ W,
                            unsigned char* __restrict__ o8, float* __restrict__ oscale, int n) {
    int t = blockIdx.x * 256 + threadIdx.x;
    int d = t >> 5;                      // one node per 32-lane half
    int lane = threadIdx.x & 63;
    int il = lane & 31;
    int hb = lane & 32;                  // half base for shuffles
    int slot = il >> 3, q = il & 7;
    float4 Wr[8];
#pragma unroll
    for (int j = 0; j < 8; j++) Wr[j] = *(const float4*)(W + (slot * 8 + j) * 32 + q * 4);
    float4 bq = *(const float4*)(bias + q * 4);
    bool act = (d < n);
    int e0 = 0, cnt = 0;
    if (act) { e0 = e_start[d]; cnt = e_start[d + 1] - e0; }
    float a0 = 0.f, a1 = 0.f, a2 = 0.f, a3 = 0.f;
    for (int c = 0; c < cnt; c += 32) {
        int rem = cnt - c; if (rem > 32) rem = 32;
        int sv = 0; float rsv = 0.f;
        if (il < rem) { sv = (int)csr[e0 + c + il]; rsv = uscale[sv]; }
        for (int i = slot; i < rem; i += 4) {
            int s = __shfl(sv, hb | i, 64);
            float rs = __shfl(rsv, hb | i, 64);
            unsigned w = *(const unsigned*)(u8 + ((size_t)s << 5) + (q << 2));
            v2f lo = __builtin_amdgcn_cvt_pk_f32_fp8(w, false);
            v2f hi = __builtin_amdgcn_cvt_pk_f32_fp8(w, true);
            a0 += rs * lo.x; a1 += rs * lo.y; a2 += rs * hi.x; a3 += rs * hi.y;
        }
    }
#pragma unroll
    for (int m = 8; m < 32; m <<= 1) {   // reduce over 4 slots (within half)
        a0 += __shfl_xor(a0, m, 64); a1 += __shfl_xor(a1, m, 64);
        a2 += __shfl_xor(a2, m, 64); a3 += __shfl_xor(a3, m, 64);
    }
    float dv = 0.f;
    if (act) {
        dv = dinv[d];
        float rs = uscale[d];
        unsigned w = *(const unsigned*)(u8 + ((size_t)d << 5) + (q << 2));
        v2f lo = __builtin_amdgcn_cvt_pk_f32_fp8(w, false);
        v2f hi = __builtin_amdgcn_cvt_pk_f32_fp8(w, true);
        a0 += rs * lo.x; a1 += rs * lo.y; a2 += rs * hi.x; a3 += rs * hi.y;
    }
    float v0 = fmaxf(dv * a0 + bq.x, 0.f);
    float v1 = fmaxf(dv * a1 + bq.y, 0.f);
    float v2 = fmaxf(dv * a2 + bq.z, 0.f);
    float v3 = fmaxf(dv * a3 + bq.w, 0.f);
    // p[q*4+e] = sum_k v[k]*W[k][q*4+e]; my k's: slot*8+j. vk from lane
    // (hb | slot*2 | (j>>2)), register j&3 (v replicated across slots).
    float p0 = 0.f, p1 = 0.f, p2 = 0.f, p3 = 0.f;
#pragma unroll
    for (int j = 0; j < 8; j++) {
        int srcl = hb | (slot << 1) | (j >> 2);
        float vk;
        switch (j & 3) {
            case 0: vk = __shfl(v0, srcl, 64); break;
            case 1: vk = __shfl(v1, srcl, 64); break;
            case 2: vk = __shfl(v2, srcl, 64); break;
            default: vk = __shfl(v3, srcl, 64); break;
        }
        p0 += vk * Wr[j].x; p1 += vk * Wr[j].y; p2 += vk * Wr[j].z; p3 += vk * Wr[j].w;
    }
#pragma unroll
    for (int m = 8; m < 32; m <<= 1) {
        p0 += __shfl_xor(p0, m, 64); p1 += __shfl_xor(p1, m, 64);
        p2 += __shfl_xor(p2, m, 64); p3 += __shfl_xor(p3, m, 64);
    }
    float o0 = dv * p0, o1 = dv * p1, o2 = dv * p2, o3 = dv * p3;
    float am = fmaxf(fmaxf(fabsf(o0), fabsf(o1)), fmaxf(fabsf(o2), fabsf(o3)));
#pragma unroll
    for (int m = 1; m < 32; m <<= 1) am = fmaxf(am, __shfl_xor(am, m, 64));
    float rm = fmaxf(am, 1e-20f);
    float sc = 128.f / rm;
    int u = 0;
    u = __builtin_amdgcn_cvt_pk_fp8_f32(o0 * sc, o1 * sc, u, false);
    u = __builtin_amdgcn_cvt_pk_fp8_f32(o2 * sc, o3 * sc, u, true);
    if (act && slot == 0) {
        *(unsigned*)(o8 + ((size_t)d << 5) + (q << 2)) = (unsigned)u;
        if (q == 0) oscale[d] = rm * (1.f / 128.f);
    }
}

// agg3: h = relu(agg) (fp32) + fused theta head; two nodes per wave.
__global__ void agg3_kernel(const unsigned char* __restrict__ u8, const float* __restrict__ uscale,
                            const int* __restrict__ e_start, const unsigned* __restrict__ csr,
                            const float* __restrict__ dinv, const float* __restrict__ bias,
                            const float* __restrict__ Wt1, const float* __restrict__ bt1,
                            const float* __restrict__ Wt2, const float* __restrict__ bt2,
                            float* __restrict__ hout, float* __restrict__ theta, int n) {
    int t = blockIdx.x * 256 + threadIdx.x;
    int d = t >> 5;
    int lane = threadIdx.x & 63;
    int il = lane & 31;
    int hb = lane & 32;
    int slot = il >> 3, q = il & 7;
    float4 Wr[8];
#pragma unroll
    for (int j = 0; j < 8; j++) Wr[j] = *(const float4*)(Wt1 + (slot * 8 + j) * 32 + q * 4);
    float4 bq = *(const float4*)(bias + q * 4);
    float4 bt = *(const float4*)(bt1 + q * 4);
    float4 w2 = *(const float4*)(Wt2 + q * 4);
    float bt2v = bt2[0];
    bool act = (d < n);
    int e0 = 0, cnt = 0;
    if (act) { e0 = e_start[d]; cnt = e_start[d + 1] - e0; }
    float a0 = 0.f, a1 = 0.f, a2 = 0.f, a3 = 0.f;
    for (int c = 0; c < cnt; c += 32) {
        int rem = cnt - c; if (rem > 32) rem = 32;
        int sv = 0; float rsv = 0.f;
        if (il < rem) { sv = (int)csr[e0 + c + il]; rsv = uscale[sv]; }
        for (int i = slot; i < rem; i += 4) {
            int s = __shfl(sv, hb | i, 64);
            float rs = __shfl(rsv, hb | i, 64);
            unsigned w = *(const unsigned*)(u8 + ((size_t)s << 5) + (q << 2));
            v2f lo = __builtin_amdgcn_cvt_pk_f32_fp8(w, false);
            v2f hi = __builtin_amdgcn_cvt_pk_f32_fp8(w, true);
            a0 += rs * lo.x; a1 += rs * lo.y; a2 += rs * hi.x; a3 += rs * hi.y;
        }
    }
#pragma unroll
    for (int m = 8; m < 32; m <<= 1) {
        a0 += __shfl_xor(a0, m, 64); a1 += __shfl_xor(a1, m, 64);
        a2 += __shfl_xor(a2, m, 64); a3 += __shfl_xor(a3, m, 64);
    }
    float dv = 0.f;
    if (act) {
        dv = dinv[d];
        float rs = uscale[d];
        unsigned w = *(const unsigned*)(u8 + ((size_t)d << 5) + (q << 2));
        v2f lo = __builtin_amdgcn_cvt_pk_f32_fp8(w, false);
        v2f hi = __builtin_amdgcn_cvt_pk_f32_fp8(w, true);
        a0 += rs * lo.x; a1 += rs * lo.y; a2 += rs * hi.x; a3 += rs * hi.y;
    }
    float v0 = fmaxf(dv * a0 + bq.x, 0.f);
    float v1 = fmaxf(dv * a1 + bq.y, 0.f);
    float v2 = fmaxf(dv * a2 + bq.z, 0.f);
    float v3 = fmaxf(dv * a3 + bq.w, 0.f);
    if (act && slot == 0) *(float4*)(hout + ((size_t)d << 5) + (q << 2)) = make_float4(v0, v1, v2, v3);
    float p0 = 0.f, p1 = 0.f, p2 = 0.f, p3 = 0.f;
#pragma unroll
    for (int j = 0; j < 8; j++) {
        int srcl = hb | (slot << 1) | (j >> 2);
        float vk;
        switch (j & 3) {
            case 0: vk = __shfl(v0, srcl, 64); break;
            case 1: vk = __shfl(v1, srcl, 64); break;
            case 2: vk = __shfl(v2, srcl, 64); break;
            default: vk = __shfl(v3, srcl, 64); break;
        }
        p0 += vk * Wr[j].x; p1 += vk * Wr[j].y; p2 += vk * Wr[j].z; p3 += vk * Wr[j].w;
    }
#pragma unroll
    for (int m = 8; m < 32; m <<= 1) {
        p0 += __shfl_xor(p0, m, 64); p1 += __shfl_xor(p1, m, 64);
        p2 += __shfl_xor(p2, m, 64); p3 += __shfl_xor(p3, m, 64);
    }
    float tl = fmaxf(p0 + bt.x, 0.f) * w2.x + fmaxf(p1 + bt.y, 0.f) * w2.y
             + fmaxf(p2 + bt.z, 0.f) * w2.z + fmaxf(p3 + bt.w, 0.f) * w2.w;
#pragma unroll
    for (int m = 1; m < 8; m <<= 1) tl += __shfl_xor(tl, m, 64);
    if (act && il == 0) theta[d] = PI_F / (1.f + __expf(-(tl + bt2v)));
}

// ---------------- heads ----------------

__global__ void pool_kernel(const float* __restrict__ h, const int* __restrict__ batch,
                            float* __restrict__ gsum, float* __restrict__ gcnt, int n) {
    int f = threadIdx.x & 31;
    int sub = threadIdx.x >> 5;
    int start = blockIdx.x * 1024 + sub * 128;
    int end = min(start + 128, n);
    if (start >= end) return;
    int curg = batch[start];
    float acc = 0.f;
    int cnt = 0;
    for (int i = start; i < end; i++) {
        int g = batch[i];
        if (g != curg) {
            atomicAdd(&gsum[curg * 32 + f], acc);
            if (f == 0) atomicAdd(&gcnt[curg], (float)cnt);
            acc = 0.f; cnt = 0; curg = g;
        }
        acc += h[i * 32 + f];
        cnt++;
    }
    atomicAdd(&gsum[curg * 32 + f], acc);
    if (f == 0) atomicAdd(&gcnt[curg], (float)cnt);
}

__global__ void bg_kernel(const float* __restrict__ gsum, const float* __restrict__ gcnt,
                          const float* __restrict__ Wg1, const float* __restrict__ bg1,
                          const float* __restrict__ Wg2, const float* __restrict__ bg2,
                          float* __restrict__ out, int G) {
    __shared__ float sW[1024];
    for (int i = threadIdx.x; i < 1024; i += 256) sW[i] = Wg1[i];
    __syncthreads();
    int t = blockIdx.x * 256 + threadIdx.x;
    int g = t >> 5;
    int lane = threadIdx.x & 63;
    int f = lane & 31, base = lane & 32;
    if (g >= G) return;
    float cnt = fmaxf(gcnt[g], 1.f);
    float hv = gsum[g * 32 + f] / cnt;
    float a = bg1[f];
#pragma unroll
    for (int k = 0; k < 32; k++) a += __shfl(hv, base | k, 64) * sW[k * 32 + f];
    a = fmaxf(a, 0.f);
    float p0 = a * Wg2[f * 2 + 0];
    float p1 = a * Wg2[f * 2 + 1];
    for (int m = 1; m < 32; m <<= 1) {
        p0 += __shfl_xor(p0, m, 64);
        p1 += __shfl_xor(p1, m, 64);
    }
    if (f == 0) {
        out[g * 2 + 0] = 2.f * PI_F / (1.f + __expf(-(p0 + bg2[0])));
        out[g * 2 + 1] = 2.f * PI_F / (1.f + __expf(-(p1 + bg2[1])));
    }
}

// ---------------- launch ----------------

extern "C" void kernel_launch(void* const* d_in, const int* in_sizes, int n_in,
                              void* d_out, int out_size, void* d_ws, size_t ws_size,
                              hipStream_t stream) {
    const float* x   = (const float*)d_in[0];
    const int*   ei  = (const int*)d_in[1];
    const int* batch = (const int*)d_in[2];
    const float* W1  = (const float*)d_in[3];
    const float* b1  = (const float*)d_in[4];
    const float* W2  = (const float*)d_in[5];
    const float* b2  = (const float*)d_in[6];
    const float* W3  = (const float*)d_in[7];
    const float* b3  = (const float*)d_in[8];
    const float* Wt1 = (const float*)d_in[9];
    const float* bt1 = (const float*)d_in[10];
    const float* Wt2 = (const float*)d_in[11];
    const float* bt2 = (const float*)d_in[12];
    const float* Wg1 = (const float*)d_in[13];
    const float* bg1 = (const float*)d_in[14];
    const float* Wg2 = (const float*)d_in[15];
    const float* bg2 = (const float*)d_in[16];

    const int N = in_sizes[0];
    const int E = in_sizes[1] / 2;
    const int G = 128;
    const int* src = ei;
    const int* dst = ei + E;
    float* theta_out = (float*)d_out;
    float* bg_out = (float*)d_out + N;

    const int NB2 = (N + BSZ - 1) >> BSH;
    const int CHUNK = (E + NBLK - 1) / NBLK;

    char* w = (char*)d_ws;
    auto alloc = [&](size_t bytes) -> char* { char* p = w; w += align256(bytes); return p; };
    int*      C        = (int*)alloc((size_t)NBLK * NB2 * 4);
    int*      colsum   = (int*)alloc((size_t)NB2 * 4);
    int*      bbase    = (int*)alloc((size_t)(NB2 + 1) * 4);
    unsigned* bkt_data = (unsigned*)alloc((size_t)E * 4);
    unsigned* csr      = (unsigned*)alloc((size_t)E * 4);
    int*      e_start  = (int*)alloc((size_t)(N + 1) * 4);
    float*    dinv     = (float*)alloc((size_t)N * 4);
    float*    xd       = (float*)alloc((size_t)N * 4);
    unsigned char* u2  = (unsigned char*)alloc((size_t)N * 32);
    float*    us2      = (float*)alloc((size_t)N * 4);
    unsigned char* u3  = (unsigned char*)alloc((size_t)N * 32);
    float*    us3      = (float*)alloc((size_t)N * 4);
    float*    hbuf     = (float*)alloc((size_t)N * 32 * 4);
    float*    gsum     = (float*)alloc((size_t)G * 32 * 4);
    float*    gcnt     = (float*)alloc((size_t)G * 4);

    hipMemsetAsync(gsum, 0, (size_t)G * 32 * 4, stream);
    hipMemsetAsync(gcnt, 0, (size_t)G * 4, stream);

    size_t ldsB = (size_t)NB2 * 4;
    count_kernel<<<NBLK, 256, ldsB, stream>>>(dst, C, E, CHUNK, NB2);
    scan_blocks_kernel<<<NB2, 256, 0, stream>>>(C, colsum, NB2);
    scan_totals_kernel<<<1, 256, 0, stream>>>(colsum, bbase, NB2, E);
    scatter_kernel<<<NBLK, 256, ldsB, stream>>>(src, dst, C, bbase, bkt_data, E, CHUNK, NB2);
    csr_build_kernel<<<NB2, 256, 0, stream>>>(bkt_data, bbase, x, csr, e_start, dinv, xd, N, NB2);

    unsigned gridNW = (unsigned)(((size_t)N * 64 + 255) / 256);  // one wave per node (agg1)
    unsigned gridNH = (unsigned)(((size_t)N * 32 + 255) / 256);  // two nodes per wave (agg2/3)

    // layer 1 (rank-1 collapse) -> fused W2 -> u2 (fp8+scale)
    agg1_kernel<<<gridNW, 256, 0, stream>>>(xd, e_start, csr, dinv, W1, b1, W2, u2, us2, N);
    // layer 2 -> fused W3 -> u3 (fp8+scale)
    agg2_kernel<<<gridNH, 256, 0, stream>>>(u2, us2, e_start, csr, dinv, b2, W3, u3, us3, N);
    // layer 3 -> h (fp32) + fused theta head
    agg3_kernel<<<gridNH, 256, 0, stream>>>(u3, us3, e_start, csr, dinv, b3,
                                            Wt1, bt1, Wt2, bt2, hbuf, theta_out, N);

    // pooled head
    pool_kernel<<<(N + 1023) / 1024, 256, 0, stream>>>(hbuf, batch, gsum, gcnt, N);
    bg_kernel<<<(G * 32 + 255) / 256, 256, 0, stream>>>(gsum, gcnt, Wg1, bg1, Wg2, bg2, bg_out, G);
}